// Round 2
// 243.269 us; speedup vs baseline: 1.0082x; 1.0082x over previous
//
#include <hip/hip_runtime.h>

// NetVLAD fp32, N=64 HW=1024 D=512 K=64. bf16 MFMA.
// R8b (resubmit; R8 run died to an infra flake, no counters returned):
// kassign stages x through wave-private LDS tiles (barrier-free,
// double-buffered 32px x 128d bf16 quarters) so global reads are 512B-
// contiguous row segments instead of 64B-granule scatters. kvlad grid is
// linearized so the 8 d-slice blocks of an image share an XCD -> at[n]
// is fetched from HBM once and L2-hit by the other 7 blocks.
//   kprep:   W[512][64] -> wt[64 k][512 d] bf16; zero a_sum/ssq.
//   kassign: s = x@W+b, softmax -> at[n*64+k][1024 hw] bf16, a_sum (atomic).
//   kvlad:   v = sum_hw x[hw][d]*a[hw][k] + a_sum*C -> out, atomic ssq.
//   kscale:  intra-norm (per n,k over d) x global L2 (per n), in place.

#define EPSF 1e-12f

typedef short bf16x8 __attribute__((ext_vector_type(8)));
typedef float f32x16 __attribute__((ext_vector_type(16)));

__device__ inline unsigned short f2bf_rne(float f) {
  union { float f; unsigned u; } v; v.f = f;
  unsigned u = v.u;
  unsigned r = u + 0x7fffu + ((u >> 16) & 1u);
  return (unsigned short)(r >> 16);
}
__device__ inline unsigned pk2(float a, float b) {
#if __has_builtin(__builtin_amdgcn_cvt_pk_bf16_f32)
  auto r = __builtin_amdgcn_cvt_pk_bf16_f32(a, b);
  return __builtin_bit_cast(unsigned, r);
#else
  return (unsigned)f2bf_rne(a) | ((unsigned)f2bf_rne(b) << 16);
#endif
}

// ---------------- K0: W transpose (blocks 0-7) + zero stats (block 8) ------
__global__ __launch_bounds__(256) void kprep(
    const float* __restrict__ Wm, unsigned short* __restrict__ wt,
    float* __restrict__ stats /* a_sum(4096) + ssq(4096) */) {
  const int t = threadIdx.x, bx = blockIdx.x;
  if (bx == 8) {
    float4 z = {0.f, 0.f, 0.f, 0.f};
#pragma unroll
    for (int r = 0; r < 8; ++r)
      *(float4*)&stats[(size_t)(r * 256 + t) * 4] = z;
    return;
  }
  __shared__ float tile[64][65];
  {
    int col = (t & 15) * 4, rbase = t >> 4;
#pragma unroll
    for (int r = 0; r < 4; ++r) {
      int row = rbase + 16 * r;
      *(float4*)&tile[row][col] =
          *(const float4*)&Wm[(size_t)(bx * 64 + row) * 64 + col];
    }
  }
  __syncthreads();
  int k = t >> 2, seg = (t & 3) * 16;
  size_t o = (size_t)k * 512 + bx * 64 + seg;
#pragma unroll
  for (int j = 0; j < 16; j += 2)
    *(unsigned*)&wt[o + j] = pk2(tile[seg + j][k], tile[seg + j + 1][k]);
}

// ---------------- Kernel A: assign GEMM + softmax -> at, a_sum -------------
// 512 blocks x 256 thr (4 independent waves, barrier-free). Wave: 32 px x 64 K.
// Stage: per 128-d quarter, load 32 full pixel-row segments (512B contiguous
// per 32-lane half) -> pk2 to bf16 -> wave-private LDS tile (XOR-swizzled).
// A-frag: ds_read_b128, lane l31 = pixel. B-frag: 16B contiguous from wt (L2).
__global__ __launch_bounds__(256) void kassign(
    const float* __restrict__ x, const unsigned short* __restrict__ wt,
    const float* __restrict__ b, unsigned short* __restrict__ at,
    float* __restrict__ a_sum) {
  const int t = threadIdx.x;
  const int w = t >> 6, lane = t & 63, l31 = lane & 31, h = lane >> 5;
  const int bx = blockIdx.x;
  const int n = bx >> 3;                    // 8 blocks per image
  const int hwbase = (bx & 7) * 128 + 32 * w;
  const size_t rowbase = (size_t)(bx * 128 + 32 * w);   // first pixel row
  const unsigned short* w0 = wt + (size_t)l31 * 512;
  const unsigned short* w1 = wt + (size_t)(32 + l31) * 512;

  // wave-private double-buffered tile: [wave][buf][32 px * 128 d] bf16 = 64 KB
  __shared__ unsigned short lds[4][2][4096];
  unsigned short (*tile)[4096] = lds[w];

  f32x16 acc0, acc1;
#pragma unroll
  for (int i = 0; i < 16; ++i) { acc0[i] = 0.f; acc1[i] = 0.f; }

#pragma unroll
  for (int q = 0; q < 4; ++q) {             // 4 quarters of 128 d
    const int buf = q & 1;
    const int dbase = q * 128;
    // ---- stage: 16 instrs, each 2 rows x 512B contiguous ----
#pragma unroll
    for (int j = 0; j < 16; ++j) {
      const int r = 2 * j + h;
      float4 v = *(const float4*)&x[(rowbase + r) * 512 + dbase + 4 * l31];
      uint2 u;
      u.x = pk2(v.x, v.y);
      u.y = pk2(v.z, v.w);
      const int idx = (r * 128 + 4 * l31) ^ (8 * (r & 7));  // ushort units
      *(uint2*)&tile[buf][idx] = u;
    }
    // ---- compute: 8 K-steps of 32x32x16 over this quarter ----
#pragma unroll
    for (int stl = 0; stl < 8; ++stl) {
      const int kd = dbase + stl * 16 + h * 8;     // global d for B frags
      const int ridx = (l31 * 128 + 16 * stl + 8 * h) ^ (8 * (l31 & 7));
      bf16x8 ax = *(const bf16x8*)&tile[buf][ridx];
      bf16x8 b0 = *(const bf16x8*)&w0[kd];
      bf16x8 b1 = *(const bf16x8*)&w1[kd];
      acc0 = __builtin_amdgcn_mfma_f32_32x32x16_bf16(ax, b0, acc0, 0, 0, 0);
      acc1 = __builtin_amdgcn_mfma_f32_32x32x16_bf16(ax, b1, acc1, 0, 0, 0);
    }
  }

  // softmax over k (lane dim: 32 lanes x {acc0,acc1}), emit at + a_sum
  const float bias0 = b[l31], bias1 = b[32 + l31];
  float a0[16], a1[16];
  float sum0 = 0.f, sum1 = 0.f;
#pragma unroll
  for (int r = 0; r < 16; ++r) {
    float s0 = acc0[r] + bias0, s1 = acc1[r] + bias1;
    float m = fmaxf(s0, s1);
#pragma unroll
    for (int msk = 1; msk < 32; msk <<= 1) m = fmaxf(m, __shfl_xor(m, msk, 64));
    float e0 = __expf(s0 - m), e1 = __expf(s1 - m);
    float S = e0 + e1;
#pragma unroll
    for (int msk = 1; msk < 32; msk <<= 1) S += __shfl_xor(S, msk, 64);
    float inv = 1.0f / S;
    a0[r] = e0 * inv; a1[r] = e1 * inv;
    sum0 += a0[r]; sum1 += a1[r];
  }
  const int hwb = hwbase + 4 * h;
  const size_t kb0 = ((size_t)n * 64 + l31) * 1024;
  const size_t kb1 = ((size_t)n * 64 + 32 + l31) * 1024;
#pragma unroll
  for (int g = 0; g < 4; ++g) {
    int hw = hwb + 8 * g;
    uint2 u;
    u.x = pk2(a0[4 * g + 0], a0[4 * g + 1]);
    u.y = pk2(a0[4 * g + 2], a0[4 * g + 3]);
    *(uint2*)&at[kb0 + hw] = u;
    u.x = pk2(a1[4 * g + 0], a1[4 * g + 1]);
    u.y = pk2(a1[4 * g + 2], a1[4 * g + 3]);
    *(uint2*)&at[kb1 + hw] = u;
  }
  sum0 += __shfl_xor(sum0, 32, 64);
  sum1 += __shfl_xor(sum1, 32, 64);
  if (lane < 32) {
    atomicAdd(&a_sum[n * 64 + l31], sum0);
    atomicAdd(&a_sum[n * 64 + 32 + l31], sum1);
  }
}

// ---------------- Kernel B: v = x^T @ a + a_sum*C -> out, atomic ssq -------
// 512 linear blocks x 256 thr (4 waves). bid = slice*64 + n, so the 8 slice
// blocks of image n have bid == n (mod 8) -> same XCD -> at[n] L2-resident.
// Wave: 32 d x 32 k, full hw=1024. A-frag: lane l31 = d-row; 8 hw values
// gathered as coalesced dword loads. B-frag: 16B contiguous from at (L2).
__global__ __launch_bounds__(256) void kvlad(
    const float* __restrict__ x, const unsigned short* __restrict__ at,
    const float* __restrict__ a_sum, const float* __restrict__ C,
    float* __restrict__ out, float* __restrict__ ssq) {
  const int t = threadIdx.x;
  const int w = t >> 6, lane = t & 63, l31 = lane & 31, h = lane >> 5;
  const int bid = blockIdx.x;
  const int n = bid & 63, d0 = (bid >> 6) * 64;
  const int dw = 32 * (w & 1), kw = 32 * (w >> 1);
  const int d = d0 + dw + l31;
  const float* xl = x + (size_t)n * 524288 + d;                 // [hw][512]
  const unsigned short* al = at + ((size_t)n * 64 + kw + l31) * 1024;

  f32x16 acc;
#pragma unroll
  for (int i = 0; i < 16; ++i) acc[i] = 0.f;

#pragma unroll 4
  for (int m = 0; m < 64; ++m) {
    const int hwb = m * 16 + h * 8;
    float a[8];
#pragma unroll
    for (int j = 0; j < 8; ++j) a[j] = xl[(size_t)(hwb + j) * 512];
    union { unsigned u[4]; bf16x8 v; } ax;
    ax.u[0] = pk2(a[0], a[1]);
    ax.u[1] = pk2(a[2], a[3]);
    ax.u[2] = pk2(a[4], a[5]);
    ax.u[3] = pk2(a[6], a[7]);
    bf16x8 bb = *(const bf16x8*)&al[hwb];
    acc = __builtin_amdgcn_mfma_f32_32x32x16_bf16(ax.v, bb, acc, 0, 0, 0);
  }

  const int k = kw + l31;
  const float as = a_sum[n * 64 + k];
  float sq = 0.f;
#pragma unroll
  for (int r = 0; r < 16; ++r) {
    int row = (r & 3) + 8 * (r >> 2) + 4 * h;
    int dd = d0 + dw + row;
    float o = acc[r] + as * C[(size_t)dd * 64 + k];
    out[((size_t)n * 512 + dd) * 64 + k] = o;
    sq += o * o;
  }
  atomicAdd(&ssq[n * 64 + k], sq);
}

// ---------------- C: scale in place ----------------
__global__ __launch_bounds__(256) void kscale(
    float* __restrict__ out, const float* __restrict__ ssq) {
  const int n = blockIdx.y, slice = blockIdx.x;
  const int t = threadIdx.x, k = t & 63, rg = t >> 6;
  __shared__ float sk[64];
  __shared__ float tot;
  if (t < 64) {
    float c = ssq[n * 64 + t];
    sk[t] = rsqrtf(c + EPSF);
    float contrib = c / (c + EPSF);
#pragma unroll
    for (int m = 32; m; m >>= 1) contrib += __shfl_xor(contrib, m, 64);
    if (t == 0) tot = rsqrtf(contrib + EPSF);
  }
  __syncthreads();
  const float scale = sk[k] * tot;
  float* vb = out + (size_t)n * 32768 + (size_t)slice * 4096;
#pragma unroll
  for (int r = rg; r < 64; r += 4) vb[r * 64 + k] *= scale;
}

extern "C" void kernel_launch(void* const* d_in, const int* in_sizes, int n_in,
                              void* d_out, int out_size, void* d_ws, size_t ws_size,
                              hipStream_t stream) {
  const float* x  = (const float*)d_in[0];   // [64,32,32,512]
  const float* Wm = (const float*)d_in[1];   // [512,64]
  const float* b  = (const float*)d_in[2];   // [64]
  const float* C  = (const float*)d_in[3];   // [512,64]
  float* out = (float*)d_out;                // [64, 32768]

  unsigned short* at = (unsigned short*)d_ws;          // 8 MiB  [n*64+k][1024]
  unsigned short* wt = at + (size_t)64 * 64 * 1024;    // 64 KiB [k][512 d]
  float* stats = (float*)(wt + (size_t)64 * 512);      // a_sum 4096 + ssq 4096
  float* a_sum = stats;
  float* ssq   = stats + 4096;

  kprep<<<dim3(9), dim3(256), 0, stream>>>(Wm, wt, stats);
  kassign<<<dim3(512), dim3(256), 0, stream>>>(x, wt, b, at, a_sum);
  kvlad<<<dim3(512), dim3(256), 0, stream>>>(x, at, a_sum, C, out, ssq);
  kscale<<<dim3(8, 64), dim3(256), 0, stream>>>(out, ssq);
}

// Round 4
// 231.299 us; speedup vs baseline: 1.0604x; 1.0518x over previous
//
#include <hip/hip_runtime.h>

// NetVLAD fp32, N=64 HW=1024 D=512 K=64. bf16 MFMA.
// R9b (identical resubmit; R9 run died to the same infra flake as R1 —
// audit found no fault/hang candidates in the kernel itself).
// FUSED assign+vlad. One kernel reads x ONCE: per 128-px slab,
// GEMM1 (s=x@W+b) from registers while scattering x^T (bf16) into a
// swizzled LDS tile; softmax in-wave -> a^T into LDS; then GEMM2
// (V[d][k] += x^T@a) entirely from LDS. Per-chunk partials (4 per image)
// are plain-written; kpost sums them + a_sum*C -> out + ssq; kscale norms.
//   kprep:  W[512][64] -> wt[64 k][512 d] bf16; zero a_sum/ssq.
//   kfused: grid 256 = (n,chunk of 256px), 4 waves, 144KB LDS, 2 slabs.
//   kpost:  out = sum_c vpart + a_sum*C; atomic ssq.
//   kscale: intra-norm (per n,k over d) x global L2 (per n), in place.

#define EPSF 1e-12f

typedef short bf16x8 __attribute__((ext_vector_type(8)));
typedef float f32x16 __attribute__((ext_vector_type(16)));

__device__ inline unsigned short f2bf_rne(float f) {
  union { float f; unsigned u; } v; v.f = f;
  unsigned u = v.u;
  unsigned r = u + 0x7fffu + ((u >> 16) & 1u);
  return (unsigned short)(r >> 16);
}
__device__ inline unsigned pk2(float a, float b) {
#if __has_builtin(__builtin_amdgcn_cvt_pk_bf16_f32)
  auto r = __builtin_amdgcn_cvt_pk_bf16_f32(a, b);
  return __builtin_bit_cast(unsigned, r);
#else
  return (unsigned)f2bf_rne(a) | ((unsigned)f2bf_rne(b) << 16);
#endif
}

// ---------------- K0: W transpose (blocks 0-7) + zero stats (block 8) ------
__global__ __launch_bounds__(256) void kprep(
    const float* __restrict__ Wm, unsigned short* __restrict__ wt,
    float* __restrict__ stats /* a_sum(4096) + ssq(4096) */) {
  const int t = threadIdx.x, bx = blockIdx.x;
  if (bx == 8) {
    float4 z = {0.f, 0.f, 0.f, 0.f};
#pragma unroll
    for (int r = 0; r < 8; ++r)
      *(float4*)&stats[(size_t)(r * 256 + t) * 4] = z;
    return;
  }
  __shared__ float tile[64][65];
  {
    int col = (t & 15) * 4, rbase = t >> 4;
#pragma unroll
    for (int r = 0; r < 4; ++r) {
      int row = rbase + 16 * r;
      *(float4*)&tile[row][col] =
          *(const float4*)&Wm[(size_t)(bx * 64 + row) * 64 + col];
    }
  }
  __syncthreads();
  int k = t >> 2, seg = (t & 3) * 16;
  size_t o = (size_t)k * 512 + bx * 64 + seg;
#pragma unroll
  for (int j = 0; j < 16; j += 2)
    *(unsigned*)&wt[o + j] = pk2(tile[seg + j][k], tile[seg + j + 1][k]);
}

// ---------------- fused assign + vlad --------------------------------------
// grid 256 blocks = (n=bid>>2, chunk c=bid&3 of 256 px). 4 waves x 64 lanes.
// LDS: xbT[512 d][128 px] bf16 (128KB, XOR-swizzled) + ab[64 k][128 px]
// (16KB) -> 144KB, 1 block/CU. Two 128-px slabs per chunk.
__global__ __launch_bounds__(256, 1) void kfused(
    const float* __restrict__ x, const unsigned short* __restrict__ wt,
    const float* __restrict__ b, float* __restrict__ vpart,
    float* __restrict__ a_sum) {
  __shared__ unsigned short xbT[512 * 128];  // [d][px ^ ((d&15)<<3)]
  __shared__ unsigned short ab[64 * 128];    // [k][px ^ ((k&15)<<3)]
  const int t = threadIdx.x;
  const int w = t >> 6, lane = t & 63, l31 = lane & 31, h = lane >> 5;
  const int bid = blockIdx.x;
  const int n = bid >> 2, c = bid & 3;
  const unsigned short* w0 = wt + (size_t)l31 * 512;
  const unsigned short* w1 = wt + (size_t)(32 + l31) * 512;
  const float bias0 = b[l31], bias1 = b[32 + l31];
  const int colpx = w * 32 + l31;            // this lane's px column (0..127)

  f32x16 accv[8];                            // [dt 0..3][kt 0..1] 128 regs
#pragma unroll
  for (int i = 0; i < 8; ++i)
#pragma unroll
    for (int j = 0; j < 16; ++j) accv[i][j] = 0.f;

  float asum0 = 0.f, asum1 = 0.f;

  for (int s = 0; s < 2; ++s) {
    const int pxb = c * 256 + s * 128;
    // ---- pass A: GEMM1 from registers + scatter x^T bf16 into LDS ----
    const float* rowp = x + ((size_t)n * 1024 + pxb + colpx) * 512;
    f32x16 s0, s1;
#pragma unroll
    for (int i = 0; i < 16; ++i) { s0[i] = 0.f; s1[i] = 0.f; }
#pragma unroll 8
    for (int st = 0; st < 32; ++st) {
      const int kd = st * 16 + h * 8;
      float4 xa = *(const float4*)&rowp[kd];
      float4 xb = *(const float4*)&rowp[kd + 4];
      union { unsigned u[4]; bf16x8 v; } ax;
      ax.u[0] = pk2(xa.x, xa.y);
      ax.u[1] = pk2(xa.z, xa.w);
      ax.u[2] = pk2(xb.x, xb.y);
      ax.u[3] = pk2(xb.z, xb.w);
      bf16x8 b0 = *(const bf16x8*)&w0[kd];
      bf16x8 b1 = *(const bf16x8*)&w1[kd];
      s0 = __builtin_amdgcn_mfma_f32_32x32x16_bf16(ax.v, b0, s0, 0, 0, 0);
      s1 = __builtin_amdgcn_mfma_f32_32x32x16_bf16(ax.v, b1, s1, 0, 0, 0);
#pragma unroll
      for (int j2 = 0; j2 < 4; ++j2) {
        const int da = kd + 2 * j2, db = da + 1;
        xbT[da * 128 + (colpx ^ ((da & 15) << 3))] =
            (unsigned short)(ax.u[j2] & 0xffffu);
        xbT[db * 128 + (colpx ^ ((db & 15) << 3))] =
            (unsigned short)(ax.u[j2] >> 16);
      }
    }
    // ---- softmax over k (lanes l31 x {s0,s1}) -> a^T into LDS ----
    float a0[16], a1[16];
    float sum0 = 0.f, sum1 = 0.f;
#pragma unroll
    for (int r = 0; r < 16; ++r) {
      float v0 = s0[r] + bias0, v1 = s1[r] + bias1;
      float m = fmaxf(v0, v1);
#pragma unroll
      for (int msk = 1; msk < 32; msk <<= 1)
        m = fmaxf(m, __shfl_xor(m, msk, 64));
      float e0 = __expf(v0 - m), e1 = __expf(v1 - m);
      float S = e0 + e1;
#pragma unroll
      for (int msk = 1; msk < 32; msk <<= 1) S += __shfl_xor(S, msk, 64);
      float inv = 1.0f / S;
      a0[r] = e0 * inv; a1[r] = e1 * inv;
      sum0 += a0[r]; sum1 += a1[r];
    }
    asum0 += sum0; asum1 += sum1;
#pragma unroll
    for (int g = 0; g < 4; ++g) {
      const int cb = w * 32 + 8 * g + 4 * h;   // 4 consecutive px
      uint2 uu;
      uu.x = pk2(a0[4 * g + 0], a0[4 * g + 1]);
      uu.y = pk2(a0[4 * g + 2], a0[4 * g + 3]);
      *(uint2*)&ab[l31 * 128 + (cb ^ ((l31 & 15) << 3))] = uu;
      uu.x = pk2(a1[4 * g + 0], a1[4 * g + 1]);
      uu.y = pk2(a1[4 * g + 2], a1[4 * g + 3]);
      *(uint2*)&ab[(32 + l31) * 128 + (cb ^ ((l31 & 15) << 3))] = uu;
    }
    __syncthreads();
    // ---- pass B: GEMM2 V[d][k] += x^T @ a from LDS ----
    const int dw = w * 128;
#pragma unroll
    for (int s8 = 0; s8 < 8; ++s8) {
      const int px0 = s8 * 16 + 8 * h;
      bf16x8 bb0 = *(const bf16x8*)&ab[l31 * 128 + (px0 ^ ((l31 & 15) << 3))];
      bf16x8 bb1 =
          *(const bf16x8*)&ab[(32 + l31) * 128 + (px0 ^ ((l31 & 15) << 3))];
#pragma unroll
      for (int dt = 0; dt < 4; ++dt) {
        const int dr = dw + dt * 32 + l31;
        bf16x8 aa = *(const bf16x8*)&xbT[dr * 128 + (px0 ^ ((dr & 15) << 3))];
        accv[dt * 2 + 0] =
            __builtin_amdgcn_mfma_f32_32x32x16_bf16(aa, bb0, accv[dt * 2 + 0], 0, 0, 0);
        accv[dt * 2 + 1] =
            __builtin_amdgcn_mfma_f32_32x32x16_bf16(aa, bb1, accv[dt * 2 + 1], 0, 0, 0);
      }
    }
    __syncthreads();   // before next slab overwrites xbT/ab
  }
  // a_sum (once per wave, both slabs)
  asum0 += __shfl_xor(asum0, 32, 64);
  asum1 += __shfl_xor(asum1, 32, 64);
  if (lane < 32) {
    atomicAdd(&a_sum[n * 64 + l31], asum0);
    atomicAdd(&a_sum[n * 64 + 32 + l31], asum1);
  }
  // epilogue: plain-write this chunk's partial V [512][64]
  float* vp = vpart + (size_t)c * 2097152 + (size_t)n * 32768;
#pragma unroll
  for (int dt = 0; dt < 4; ++dt) {
#pragma unroll
    for (int kt = 0; kt < 2; ++kt) {
      const f32x16 a = accv[dt * 2 + kt];
      const int kcol = kt * 32 + l31;
#pragma unroll
      for (int r = 0; r < 16; ++r) {
        const int drow = w * 128 + dt * 32 + (r & 3) + 8 * (r >> 2) + 4 * h;
        vp[drow * 64 + kcol] = a[r];
      }
    }
  }
}

// ---------------- kpost: out = sum_c vpart + a_sum*C; atomic ssq -----------
__global__ __launch_bounds__(256) void kpost(
    const float* __restrict__ vpart, const float* __restrict__ a_sum,
    const float* __restrict__ C, float* __restrict__ out,
    float* __restrict__ ssq) {
  const int bid = blockIdx.x;               // 512: n fast for XCD locality
  const int n = bid & 63, d0 = (bid >> 6) * 64;
  const int t = threadIdx.x, k = t & 63, dr = t >> 6;
  const float as = a_sum[n * 64 + k];
  const size_t nb = (size_t)n * 32768;
  float sq = 0.f;
#pragma unroll
  for (int r = 0; r < 16; ++r) {
    const int d = d0 + dr * 16 + r;
    const size_t idx = nb + (size_t)d * 64 + k;
    float o = vpart[idx] + vpart[idx + 2097152] + vpart[idx + 4194304] +
              vpart[idx + 6291456] + as * C[(size_t)d * 64 + k];
    out[idx] = o;
    sq += o * o;
  }
  atomicAdd(&ssq[n * 64 + k], sq);
}

// ---------------- kscale: normalize in place -------------------------------
__global__ __launch_bounds__(256) void kscale(
    float* __restrict__ out, const float* __restrict__ ssq) {
  const int n = blockIdx.y, slice = blockIdx.x;
  const int t = threadIdx.x, k = t & 63, rg = t >> 6;
  __shared__ float sk[64];
  __shared__ float tot;
  if (t < 64) {
    float cc = ssq[n * 64 + t];
    sk[t] = rsqrtf(cc + EPSF);
    float contrib = cc / (cc + EPSF);
#pragma unroll
    for (int m = 32; m; m >>= 1) contrib += __shfl_xor(contrib, m, 64);
    if (t == 0) tot = rsqrtf(contrib + EPSF);
  }
  __syncthreads();
  const float scale = sk[k] * tot;
  float* vb = out + (size_t)n * 32768 + (size_t)slice * 4096;
#pragma unroll
  for (int r = rg; r < 64; r += 4) vb[r * 64 + k] *= scale;
}

extern "C" void kernel_launch(void* const* d_in, const int* in_sizes, int n_in,
                              void* d_out, int out_size, void* d_ws, size_t ws_size,
                              hipStream_t stream) {
  const float* x  = (const float*)d_in[0];   // [64,32,32,512]
  const float* Wm = (const float*)d_in[1];   // [512,64]
  const float* b  = (const float*)d_in[2];   // [64]
  const float* C  = (const float*)d_in[3];   // [512,64]
  float* out = (float*)d_out;                // [64, 32768]

  float* vpart = (float*)d_ws;                         // 32 MiB: 4 x [64][512][64]
  unsigned short* wt = (unsigned short*)(vpart + 4 * 2097152);  // 64 KiB
  float* stats = (float*)(wt + (size_t)64 * 512);      // a_sum 4096 + ssq 4096
  float* a_sum = stats;
  float* ssq   = stats + 4096;

  kprep<<<dim3(9), dim3(256), 0, stream>>>(Wm, wt, stats);
  kfused<<<dim3(256), dim3(256), 0, stream>>>(x, wt, b, vpart, a_sum);
  kpost<<<dim3(512), dim3(256), 0, stream>>>(vpart, a_sum, C, out, ssq);
  kscale<<<dim3(8, 64), dim3(256), 0, stream>>>(out, ssq);
}